// Round 6
// baseline (500.194 us; speedup 1.0000x reference)
//
#include <hip/hip_runtime.h>
#include <cstdint>
#include <cstddef>

typedef unsigned short ushort;
typedef __attribute__((ext_vector_type(8))) short short8;    // 8 x bf16 (4 VGPRs)
typedef __attribute__((ext_vector_type(16))) float f32x16;   // 32x32 accumulator

__device__ __forceinline__ float bf2f(ushort u) {
  union { unsigned u; float f; } c; c.u = ((unsigned)u) << 16; return c.f;
}
__device__ __forceinline__ ushort f2bf(float f) {
  union { float f; unsigned u; } c; c.f = f;
  unsigned u = c.u;
  return (ushort)((u + 0x7fffu + ((u >> 16) & 1u)) >> 16);   // RNE
}

#define G2L(g, l) __builtin_amdgcn_global_load_lds( \
    (const __attribute__((address_space(1))) void*)(g), \
    (__attribute__((address_space(3))) void*)(l), 16, 0, 0)

// ---------------- MFMA GEMM: C[M,N] = A[M,K] . B[N,K]^T (+bias) ----------------
// Block tile 256x128 (M x N), BK=64, 4 waves in 2x2; each wave 128x64 via
// 4m x 2n MFMA 32x32x16 tiles -> 0.75 ds_read_b128 per MFMA, 128 MFMA/barrier.
// LDS: As[256][64], Bs[128][64], row stride 128 B. Swizzle: global chunk q of
// row r stored at LDS chunk (q + f(r)) & 7 with f(r) = (r + (r>>3)) & 7.
//   Read chunk for lane l = ((l>>5) + 2h + (l&7) + ((l>>3)&3)) & 7:
//   distinct over every 8-lane run AND over {l,l+8,l+16,l+24}  (R3-derived
//   conflict-freedom criterion; R4/R5's chunk was l+8-invariant -> 4-way).
// MODE 0: stage1 qkv  (bias fp32, write bf16)
// MODE 1: stage2 scores / MODE 2: stage4 PV (no bias, write bf16)
// MODE 3: stage5 out  (bias fp32, write fp32 split at col 512)
struct MArgs {
  const ushort* A; int lda; long asz;
  const ushort* B; int ldb; long bsz;
  void* C; int ldc; long csz;
  int K;
  const float* bias;
  float* C2;
};

template<int MODE>
__launch_bounds__(256)
__global__ void mfma_gemm(MArgs g) {
  __shared__ ushort As[256 * 64];
  __shared__ ushort Bs[128 * 64];
  const int tid = threadIdx.x;
  const int lane = tid & 63;
  const int wave = tid >> 6;
  const int z = blockIdx.z;
  const long m0 = (long)blockIdx.y * 256;
  const long n0 = (long)blockIdx.x * 128;
  const ushort* A = g.A + (long)z * g.asz;
  const ushort* B = g.B + (long)z * g.bsz;

  // ---- staging: thread -> row srow (in 32-row group), LDS chunk tid&7.
  // stored global chunk = (ldschunk - f(srow)) & 7
  const int srow = tid >> 3;                                   // 0..31
  const int fs = (srow + (srow >> 3)) & 7;
  const int sk = (((tid & 7) - fs) & 7) * 8;                   // global k-offset (elems)
  const ushort* ga[8]; const ushort* gb[4];
  ushort* la[8]; ushort* lb[4];
#pragma unroll
  for (int gp = 0; gp < 8; ++gp) {
    ga[gp] = A + (m0 + gp * 32 + srow) * g.lda + sk;
    la[gp] = As + gp * 2048 + tid * 8;
  }
#pragma unroll
  for (int gp = 0; gp < 4; ++gp) {
    gb[gp] = B + (n0 + gp * 32 + srow) * g.ldb + sk;
    lb[gp] = Bs + gp * 2048 + tid * 8;
  }

  // ---- fragment read addresses
  // lane l: row = l&31, needs global chunk (l>>5)+2h -> LDS chunk cbase+2h
  const int wm = (wave >> 1) * 128;
  const int wn = (wave & 1) * 64;
  const int fr = lane & 31;
  const ushort* rA = As + (wm + fr) * 64;
  const ushort* rB = Bs + (wn + fr) * 64;
  const int cbase = ((lane >> 5) + (lane & 7) + ((lane >> 3) & 3)) & 7;
  int offk[4];
#pragma unroll
  for (int h = 0; h < 4; ++h) offk[h] = ((cbase + 2 * h) & 7) * 8;

  f32x16 acc[4][2];
#pragma unroll
  for (int i = 0; i < 4; ++i)
#pragma unroll
    for (int j = 0; j < 2; ++j)
#pragma unroll
      for (int r = 0; r < 16; ++r) acc[i][j][r] = 0.f;

  for (int k0 = 0; k0 < g.K; k0 += 64) {
#pragma unroll
    for (int gp = 0; gp < 8; ++gp) G2L(ga[gp] + k0, la[gp]);
#pragma unroll
    for (int gp = 0; gp < 4; ++gp) G2L(gb[gp] + k0, lb[gp]);
    __syncthreads();
#pragma unroll
    for (int h = 0; h < 4; ++h) {
      short8 bf0 = *(const short8*)(rB + offk[h]);
      short8 bf1 = *(const short8*)(rB + 2048 + offk[h]);
      short8 a0 = *(const short8*)(rA + offk[h]);
      short8 a1 = *(const short8*)(rA + 2048 + offk[h]);
      short8 a2 = *(const short8*)(rA + 4096 + offk[h]);
      short8 a3 = *(const short8*)(rA + 6144 + offk[h]);
      acc[0][0] = __builtin_amdgcn_mfma_f32_32x32x16_bf16(a0, bf0, acc[0][0], 0, 0, 0);
      acc[0][1] = __builtin_amdgcn_mfma_f32_32x32x16_bf16(a0, bf1, acc[0][1], 0, 0, 0);
      acc[1][0] = __builtin_amdgcn_mfma_f32_32x32x16_bf16(a1, bf0, acc[1][0], 0, 0, 0);
      acc[1][1] = __builtin_amdgcn_mfma_f32_32x32x16_bf16(a1, bf1, acc[1][1], 0, 0, 0);
      acc[2][0] = __builtin_amdgcn_mfma_f32_32x32x16_bf16(a2, bf0, acc[2][0], 0, 0, 0);
      acc[2][1] = __builtin_amdgcn_mfma_f32_32x32x16_bf16(a2, bf1, acc[2][1], 0, 0, 0);
      acc[3][0] = __builtin_amdgcn_mfma_f32_32x32x16_bf16(a3, bf0, acc[3][0], 0, 0, 0);
      acc[3][1] = __builtin_amdgcn_mfma_f32_32x32x16_bf16(a3, bf1, acc[3][1], 0, 0, 0);
    }
    __syncthreads();
  }

  // ---- epilogue: C/D map (m74/m101): col=lane&31, row=(reg&3)+8*(reg>>2)+4*(lane>>5)
  const int cc = lane & 31;
  const int rbase = 4 * (lane >> 5);
  ushort* Cu = (ushort*)g.C + (long)z * g.csz;
  float* Cf = (float*)g.C;
#pragma unroll
  for (int mt = 0; mt < 4; ++mt) {
#pragma unroll
    for (int nt = 0; nt < 2; ++nt) {
      const long col = n0 + wn + nt * 32 + cc;
      float bv = 0.f;
      if (MODE == 0 || MODE == 3) bv = g.bias[col];
#pragma unroll
      for (int r = 0; r < 16; ++r) {
        const long row = m0 + wm + mt * 32 + (r & 3) + 8 * (r >> 2) + rbase;
        float v = acc[mt][nt][r] + bv;
        if (MODE == 3) {
          float* dst = (col < 512) ? (Cf + row * 512 + col) : (g.C2 + row * 512 + (col - 512));
          *dst = v;
        } else {
          Cu[row * (long)g.ldc + col] = f2bf(v);
        }
      }
    }
  }
}

// ---------------- converts ----------------
__global__ void cvt_x6(const float* x0, const float* x1, const float* x2,
                       const float* x3, const float* x4, const float* x5, ushort* X) {
  const long m = blockIdx.y;
  const int c4 = (blockIdx.x * 256 + threadIdx.x) * 4;  // 0..3071
  const int p = c4 >> 9, d = c4 & 511;
  const float* xp;
  switch (p) {
    case 0: xp = x0; break; case 1: xp = x1; break; case 2: xp = x2; break;
    case 3: xp = x3; break; case 4: xp = x4; break; default: xp = x5; break;
  }
  float4 v = *(const float4*)(xp + m * 512 + d);
  ushort4 o; o.x = f2bf(v.x); o.y = f2bf(v.y); o.z = f2bf(v.z); o.w = f2bf(v.w);
  *(ushort4*)(X + m * 3072 + c4) = o;
}

__device__ __forceinline__ int chunk_map(int c) { return (c == 0) ? 0 : (c == 1) ? 2 : (c == 2) ? 4 : 5; }

__global__ void cvt_w4(const float* W, ushort* Wq4) {
  const long r = blockIdx.y;                       // 0..2047
  const int c4 = (blockIdx.x * 256 + threadIdx.x) * 4;
  const long wr = (long)chunk_map((int)(r >> 9)) * 512 + (r & 511);
  float4 v = *(const float4*)(W + wr * 3072 + c4);
  ushort4 o; o.x = f2bf(v.x); o.y = f2bf(v.y); o.z = f2bf(v.z); o.w = f2bf(v.w);
  *(ushort4*)(Wq4 + r * 3072 + c4) = o;
}

__global__ void cvt_wout(const float* W, ushort* Wo) {
  const long r = blockIdx.y;
  const int c4 = threadIdx.x * 4;
  float4 v = *(const float4*)(W + r * 1024 + c4);
  ushort4 o; o.x = f2bf(v.x); o.y = f2bf(v.y); o.z = f2bf(v.z); o.w = f2bf(v.w);
  *(ushort4*)(Wo + r * 1024 + c4) = o;
}

__global__ void mk_bias4(const float* bqkv, float* b4) {
  const int n = blockIdx.x * 256 + threadIdx.x;    // 0..2047
  b4[n] = bqkv[chunk_map(n >> 9) * 512 + (n & 511)];
}

// ---------------- V transpose: Vt_b[n][k] = QKV[b*2048+k][1024+n] ----------------
__global__ void transpose_v(const ushort* QKV, ushort* Vt) {
  __shared__ ushort t[64][65];
  const int tid = threadIdx.x;
  const int k0 = blockIdx.x * 64, n0 = blockIdx.y * 64, b = blockIdx.z;
  const ushort* src = QKV + (long)b * 2048 * 2048 + 1024;
#pragma unroll
  for (int i = 0; i < 16; ++i) {
    int idx = i * 256 + tid; int r = idx >> 6, c = idx & 63;
    t[r][c] = src[(long)(k0 + r) * 2048 + (n0 + c)];
  }
  __syncthreads();
  ushort* dst = Vt + (long)b * 1024 * 2048;
#pragma unroll
  for (int i = 0; i < 16; ++i) {
    int idx = i * 256 + tid; int r = idx >> 6, c = idx & 63;
    dst[(long)(n0 + r) * 2048 + (k0 + c)] = t[c][r];
  }
}

// ---------------- softmax: lane owns one contiguous 64B chunk (32 elems) ----------------
__launch_bounds__(256)
__global__ void softmax_rows(ushort* S, const int* mask) {
  const int lane = threadIdx.x & 63;
  const int wave = threadIdx.x >> 6;
  const long row = (long)blockIdx.x * 4 + wave;            // 0..8191
  const int* m = mask + (row >> 11) * 2048 + lane * 32;
  ushort* s = S + row * 2048 + lane * 32;
  const float scale = 0.04419417382415922f;                // 512^-0.5

  short8 raw[4];
#pragma unroll
  for (int i = 0; i < 4; ++i) raw[i] = *(const short8*)(s + i * 8);
  int4 mi[8];
#pragma unroll
  for (int i = 0; i < 8; ++i) mi[i] = *(const int4*)(m + i * 4);

  float v[32];
  int mk[32];
#pragma unroll
  for (int i = 0; i < 8; ++i) {
    mk[i * 4 + 0] = mi[i].x; mk[i * 4 + 1] = mi[i].y;
    mk[i * 4 + 2] = mi[i].z; mk[i * 4 + 3] = mi[i].w;
  }
#pragma unroll
  for (int i = 0; i < 32; ++i) v[i] = bf2f((ushort)raw[i >> 3][i & 7]) * scale;

  float mx = -INFINITY;
#pragma unroll
  for (int i = 0; i < 32; ++i) if (!mk[i]) mx = fmaxf(mx, v[i]);
#pragma unroll
  for (int off = 32; off; off >>= 1) mx = fmaxf(mx, __shfl_xor(mx, off));

  float sum = 0.f;
#pragma unroll
  for (int i = 0; i < 32; ++i) {
    float e = mk[i] ? 0.f : __expf(v[i] - mx);
    v[i] = e;
    sum += e;
  }
#pragma unroll
  for (int off = 32; off; off >>= 1) sum += __shfl_xor(sum, off);

  float r = 1.f / sum;
  short8 out[4];
#pragma unroll
  for (int i = 0; i < 32; ++i) out[i >> 3][i & 7] = (short)f2bf(v[i] * r);
#pragma unroll
  for (int i = 0; i < 4; ++i) *(short8*)(s + i * 8) = out[i];
}

// ---------------- launcher ----------------
extern "C" void kernel_launch(void* const* d_in, const int* in_sizes, int n_in,
                              void* d_out, int out_size, void* d_ws, size_t ws_size,
                              hipStream_t stream) {
  const float* qr = (const float*)d_in[0];
  const float* qi = (const float*)d_in[1];
  const float* kr = (const float*)d_in[2];
  const float* ki = (const float*)d_in[3];
  const float* vr = (const float*)d_in[4];
  const float* vi = (const float*)d_in[5];
  const int* pm = (const int*)d_in[6];
  const float* Wqkv = (const float*)d_in[7];
  const float* bqkv = (const float*)d_in[8];
  const float* Wout = (const float*)d_in[9];
  const float* bout = (const float*)d_in[10];
  float* out = (float*)d_out;

  // ws layout (bytes):
  char* base = (char*)d_ws;
  ushort* QKV   = (ushort*)(base);                         // 8192x2048 bf16   33,554,432
  ushort* Wq4   = (ushort*)(base + 33554432);              // 2048x3072 bf16   12,582,912
  ushort* Wo    = (ushort*)(base + 46137344);              // 1024x1024 bf16    2,097,152
  float*  b4    = (float*) (base + 48234496);              // 2048 fp32             8,192
  char*   uni   = base + 48242688;
  ushort* Xbf   = (ushort*)(uni);                          // 8192x3072 bf16   50,331,648 (dies after stage1)
  ushort* Vt    = (ushort*)(uni);                          // 4x1024x2048 bf16 16,777,216
  ushort* S     = (ushort*)(uni + 16777216);               // 4x2048x2048 bf16 33,554,432
  ushort* AO    = (ushort*)(uni + 50331648);               // 8192x1024 bf16   16,777,216
  // total 115,351,552 bytes

  // converts
  cvt_x6<<<dim3(3, 8192), 256, 0, stream>>>(qr, qi, kr, ki, vr, vi, Xbf);
  cvt_w4<<<dim3(3, 2048), 256, 0, stream>>>(Wqkv, Wq4);
  cvt_wout<<<dim3(1, 1024), 256, 0, stream>>>(Wout, Wo);
  mk_bias4<<<8, 256, 0, stream>>>(bqkv, b4);

  // stage 1: QKV = Xbf(8192x3072) . Wq4(2048x3072)^T + b4  -> bf16
  {
    MArgs a{};
    a.A = Xbf; a.lda = 3072; a.asz = 0;
    a.B = Wq4; a.ldb = 3072; a.bsz = 0;
    a.C = QKV; a.ldc = 2048; a.csz = 0;
    a.K = 3072; a.bias = b4;
    mfma_gemm<0><<<dim3(16, 32, 1), 256, 0, stream>>>(a);
  }

  // V transpose (reads QKV cols 1024..2047)
  transpose_v<<<dim3(32, 16, 4), 256, 0, stream>>>(QKV, Vt);

  // stage 2: S_b = Q_b(2048x512) . K_b(2048x512)^T  -> bf16 (raw scores)
  {
    MArgs a{};
    a.A = QKV;        a.lda = 2048; a.asz = (long)2048 * 2048;
    a.B = QKV + 512;  a.ldb = 2048; a.bsz = (long)2048 * 2048;
    a.C = S;          a.ldc = 2048; a.csz = (long)2048 * 2048;
    a.K = 512;
    mfma_gemm<1><<<dim3(16, 8, 4), 256, 0, stream>>>(a);
  }

  // stage 3: softmax rows in place (scale + mask + exp + norm)
  softmax_rows<<<2048, 256, 0, stream>>>(S, pm);

  // stage 4: AO_b = P_b(2048x2048) . Vt_b(1024x2048)^T  -> bf16
  {
    MArgs a{};
    a.A = S;  a.lda = 2048; a.asz = (long)2048 * 2048;
    a.B = Vt; a.ldb = 2048; a.bsz = (long)1024 * 2048;
    a.C = AO; a.ldc = 1024; a.csz = (long)2048 * 1024;
    a.K = 2048;
    mfma_gemm<2><<<dim3(8, 8, 4), 256, 0, stream>>>(a);
  }

  // stage 5: out = AO(8192x1024) . Wo(1024x1024)^T + bout -> fp32 split
  {
    MArgs a{};
    a.A = AO; a.lda = 1024; a.asz = 0;
    a.B = Wo; a.ldb = 1024; a.bsz = 0;
    a.C = out; a.ldc = 512; a.csz = 0;
    a.C2 = out + (long)8192 * 512;
    a.K = 1024; a.bias = bout;
    mfma_gemm<3><<<dim3(8, 32, 1), 256, 0, stream>>>(a);
  }
}